// Round 1
// baseline (1865.554 us; speedup 1.0000x reference)
//
#include <hip/hip_runtime.h>
#include <hip/hip_fp16.h>
#include <math.h>

#define NB 4
#define NN 4096
#define NC 128
#define MU (1.0f/8192.0f)
#define NBLK 256   // row-panel blocks per batch (16 rows each) in fused sinkhorn pass
#define NFIN 4     // finalize blocks per batch (col-sum partial slots)

// ---------------- scalars ----------------
__global__ void scalars_k(const float* __restrict__ ds, const float* __restrict__ gw,
                          const float* __restrict__ ct, float* __restrict__ scal) {
    if (threadIdx.x == 0) {
        float t = ct[0];
        scal[0] = 1.0f / t;                                   // raw temp reciprocal (scores = sim/temp_raw)
        float tc = fminf(fmaxf(t, 0.03f), 10.0f);
        float d = fminf(fmaxf(ds[0] / tc, -50.0f), 50.0f);
        scal[1] = __expf(d);                                  // kd = exp(dustbin/temp_clipped)
        scal[2] = fminf(fmaxf(gw[0], 0.0f), 2.0f);            // clipped geo weight
    }
}

// ---------------- inverse norms ----------------
__global__ __launch_bounds__(256) void invnorm_k(const float* __restrict__ fA, const float* __restrict__ fB,
                                                 float* __restrict__ invA, float* __restrict__ invB) {
    int wv = blockIdx.x * 4 + (threadIdx.x >> 6);   // 0..32767
    int lane = threadIdx.x & 63;
    const float* src;
    float* dst;
    if (wv < NB * NN) { src = fA + (size_t)wv * NC; dst = invA + wv; }
    else              { src = fB + (size_t)(wv - NB * NN) * NC; dst = invB + (wv - NB * NN); }
    float2 x = *(const float2*)(src + 2 * lane);
    float ss = x.x * x.x + x.y * x.y;
#pragma unroll
    for (int off = 32; off; off >>= 1) ss += __shfl_down(ss, off);
    if (lane == 0) *dst = 1.0f / fmaxf(sqrtf(ss), 1e-12f);
}

// ---------------- fp32 GEMM: raw_sim ----------------
__global__ __launch_bounds__(256) void gemm_k(const float* __restrict__ A, const float* __restrict__ B,
                                              const float* __restrict__ invA, const float* __restrict__ invB,
                                              float* __restrict__ sim_out) {
    __shared__ float As[16][128];
    __shared__ float Bs[16][128];
    int b = blockIdx.z;
    int m0 = blockIdx.y * 128, n0 = blockIdx.x * 128;
    const float* Ab = A + (size_t)b * NN * NC;
    const float* Bb = B + (size_t)b * NN * NC;
    int t = threadIdx.x;
    int tr = t >> 2, tq = t & 3;
    int ty = t >> 4, tx = t & 15;
    float acc[8][8] = {};
    for (int k0 = 0; k0 < NC; k0 += 16) {
        float4 a0 = *(const float4*)(Ab + (size_t)(m0 + tr) * NC + k0 + 4 * tq);
        float4 a1 = *(const float4*)(Ab + (size_t)(m0 + tr + 64) * NC + k0 + 4 * tq);
        float4 b0 = *(const float4*)(Bb + (size_t)(n0 + tr) * NC + k0 + 4 * tq);
        float4 b1 = *(const float4*)(Bb + (size_t)(n0 + tr + 64) * NC + k0 + 4 * tq);
        __syncthreads();
        As[4 * tq + 0][tr] = a0.x; As[4 * tq + 1][tr] = a0.y; As[4 * tq + 2][tr] = a0.z; As[4 * tq + 3][tr] = a0.w;
        As[4 * tq + 0][tr + 64] = a1.x; As[4 * tq + 1][tr + 64] = a1.y; As[4 * tq + 2][tr + 64] = a1.z; As[4 * tq + 3][tr + 64] = a1.w;
        Bs[4 * tq + 0][tr] = b0.x; Bs[4 * tq + 1][tr] = b0.y; Bs[4 * tq + 2][tr] = b0.z; Bs[4 * tq + 3][tr] = b0.w;
        Bs[4 * tq + 0][tr + 64] = b1.x; Bs[4 * tq + 1][tr + 64] = b1.y; Bs[4 * tq + 2][tr + 64] = b1.z; Bs[4 * tq + 3][tr + 64] = b1.w;
        __syncthreads();
#pragma unroll
        for (int k = 0; k < 16; k++) {
            float av[8], bv[8];
            *(float4*)av = *(const float4*)&As[k][ty * 8];
            *(float4*)(av + 4) = *(const float4*)&As[k][ty * 8 + 4];
            *(float4*)bv = *(const float4*)&Bs[k][tx * 8];
            *(float4*)(bv + 4) = *(const float4*)&Bs[k][tx * 8 + 4];
#pragma unroll
            for (int i = 0; i < 8; i++)
#pragma unroll
                for (int j = 0; j < 8; j++) acc[i][j] = fmaf(av[i], bv[j], acc[i][j]);
        }
    }
    int m_base = m0 + ty * 8;
    int n_base = n0 + tx * 8;
    float ib[8];
#pragma unroll
    for (int j = 0; j < 8; j++) ib[j] = invB[(size_t)b * NN + n_base + j];
#pragma unroll
    for (int i = 0; i < 8; i++) {
        int m = m_base + i;
        float ia = invA[(size_t)b * NN + m];
        float row[8];
#pragma unroll
        for (int j = 0; j < 8; j++) row[j] = acc[i][j] * ia * ib[j];
        size_t rbase = ((size_t)b * NN + m) * NN + n_base;
        float4* so = (float4*)(sim_out + rbase);
        so[0] = make_float4(row[0], row[1], row[2], row[3]);
        so[1] = make_float4(row[4], row[5], row[6], row[7]);
    }
}

__device__ __forceinline__ float kval(float s, float ict) {
    float z = fminf(fmaxf(s * ict, -50.0f), 50.0f);
    return __expf(z);
}

// ---------------- Sinkhorn init ----------------
// cperm = 1 everywhere (layout-independent); state slot A: c_dust=1, csum partials sum to 4096.
__global__ void init_sink2_k(float* __restrict__ cperm, float* __restrict__ st) {
    int i = blockIdx.x * 256 + threadIdx.x;   // 0..16383
    if (i < NB * NN) cperm[i] = 1.0f;
    if (i < NB) st[i] = 1.0f;
    if (i < NB * NFIN) st[NB + i] = (float)NN / (float)NFIN;
}

// ---------------- fused Sinkhorn row+col pass ----------------
// One read of K per iteration. Block owns 16 rows (4 per warp). Per row:
//   r_m = MU / (sum_n K_mn c_n + kd*c_dust);  then colacc[n] += K_mn * r_m (K row held in regs).
// Deterministic: butterfly reduce (fixed tree), serialized warp->LDS adds, fixed-order finalize.
// c is stored PERMUTED: float4 slot p = s*128 + h*64 + l holds cols n = 512s + 8l + 4h + {0..3}.
__global__ __launch_bounds__(256) void sink_rc_k(const float* __restrict__ sim,
        const float* __restrict__ cperm, const float* __restrict__ stPrev,
        float* __restrict__ r, float* __restrict__ rsum_part, float* __restrict__ colpart,
        const float* __restrict__ scal) {
    __shared__ float4 cls[1024];   // permuted c (16 KB)
    __shared__ float4 red[1024];   // cross-warp col-partial reduction (16 KB)
    __shared__ float wsum[4];
    int b = blockIdx.y, blk = blockIdx.x;
    int t = threadIdx.x, w = t >> 6, lane = t & 63;
    float kd = scal[1], ict = scal[0];
    float c_dust = stPrev[b];
    const float4* cp = (const float4*)cperm + (size_t)b * 1024;
#pragma unroll
    for (int q = 0; q < 4; q++) cls[t + 256 * q] = cp[t + 256 * q];
    __syncthreads();
    float colacc[64];
#pragma unroll
    for (int q = 0; q < 64; q++) colacc[q] = 0.0f;
    float rsum = 0.0f;
    const float* Sb = sim + (size_t)b * NN * NN;
#pragma unroll 1
    for (int i = 0; i < 4; i++) {
        int m = blk * 16 + w * 4 + i;
        const float4* Srow = (const float4*)(Sb + (size_t)m * NN);
        float kv[64];
        float acc0 = 0.0f, acc1 = 0.0f;
#pragma unroll
        for (int s = 0; s < 8; s++) {
            float4 v0 = Srow[128 * s + 2 * lane];
            float4 v1 = Srow[128 * s + 2 * lane + 1];
            float4 c0 = cls[128 * s + lane];
            float4 c1 = cls[128 * s + 64 + lane];
            float k0 = kval(v0.x, ict), k1 = kval(v0.y, ict), k2 = kval(v0.z, ict), k3 = kval(v0.w, ict);
            float k4 = kval(v1.x, ict), k5 = kval(v1.y, ict), k6 = kval(v1.z, ict), k7 = kval(v1.w, ict);
            kv[8 * s + 0] = k0; kv[8 * s + 1] = k1; kv[8 * s + 2] = k2; kv[8 * s + 3] = k3;
            kv[8 * s + 4] = k4; kv[8 * s + 5] = k5; kv[8 * s + 6] = k6; kv[8 * s + 7] = k7;
            acc0 = fmaf(k0, c0.x, acc0); acc0 = fmaf(k1, c0.y, acc0);
            acc0 = fmaf(k2, c0.z, acc0); acc0 = fmaf(k3, c0.w, acc0);
            acc1 = fmaf(k4, c1.x, acc1); acc1 = fmaf(k5, c1.y, acc1);
            acc1 = fmaf(k6, c1.z, acc1); acc1 = fmaf(k7, c1.w, acc1);
        }
        float acc = acc0 + acc1;
#pragma unroll
        for (int off = 1; off < 64; off <<= 1) acc += __shfl_xor(acc, off);   // all lanes identical, fixed tree
        float rm = MU / (acc + kd * c_dust);
        if (lane == 0) r[(size_t)b * NN + m] = rm;
        rsum += rm;
#pragma unroll
        for (int q = 0; q < 64; q++) colacc[q] = fmaf(kv[q], rm, colacc[q]);
    }
    if (lane == 0) wsum[w] = rsum;
    __syncthreads();
    if (w == 0) {
#pragma unroll
        for (int s = 0; s < 8; s++) {
            red[128 * s + lane]      = make_float4(colacc[8 * s + 0], colacc[8 * s + 1], colacc[8 * s + 2], colacc[8 * s + 3]);
            red[128 * s + 64 + lane] = make_float4(colacc[8 * s + 4], colacc[8 * s + 5], colacc[8 * s + 6], colacc[8 * s + 7]);
        }
    }
    __syncthreads();
    if (w == 1) {
#pragma unroll
        for (int s = 0; s < 8; s++) {
            float4 x = red[128 * s + lane];
            x.x += colacc[8 * s + 0]; x.y += colacc[8 * s + 1]; x.z += colacc[8 * s + 2]; x.w += colacc[8 * s + 3];
            red[128 * s + lane] = x;
            float4 y = red[128 * s + 64 + lane];
            y.x += colacc[8 * s + 4]; y.y += colacc[8 * s + 5]; y.z += colacc[8 * s + 6]; y.w += colacc[8 * s + 7];
            red[128 * s + 64 + lane] = y;
        }
    }
    __syncthreads();
    if (w == 2) {
#pragma unroll
        for (int s = 0; s < 8; s++) {
            float4 x = red[128 * s + lane];
            x.x += colacc[8 * s + 0]; x.y += colacc[8 * s + 1]; x.z += colacc[8 * s + 2]; x.w += colacc[8 * s + 3];
            red[128 * s + lane] = x;
            float4 y = red[128 * s + 64 + lane];
            y.x += colacc[8 * s + 4]; y.y += colacc[8 * s + 5]; y.z += colacc[8 * s + 6]; y.w += colacc[8 * s + 7];
            red[128 * s + 64 + lane] = y;
        }
    }
    __syncthreads();
    if (w == 3) {
#pragma unroll
        for (int s = 0; s < 8; s++) {
            float4 x = red[128 * s + lane];
            x.x += colacc[8 * s + 0]; x.y += colacc[8 * s + 1]; x.z += colacc[8 * s + 2]; x.w += colacc[8 * s + 3];
            red[128 * s + lane] = x;
            float4 y = red[128 * s + 64 + lane];
            y.x += colacc[8 * s + 4]; y.y += colacc[8 * s + 5]; y.z += colacc[8 * s + 6]; y.w += colacc[8 * s + 7];
            red[128 * s + 64 + lane] = y;
        }
    }
    __syncthreads();
    float4* op = (float4*)colpart + ((size_t)b * NBLK + blk) * 1024;
#pragma unroll
    for (int q = 0; q < 4; q++) op[t + 256 * q] = red[t + 256 * q];
    if (t == 0) rsum_part[b * NBLK + blk] = ((wsum[0] + wsum[1]) + wsum[2]) + wsum[3];
}

// ---------------- Sinkhorn col finalize ----------------
// c_n = MU / (sum_blk colpart + kd*r_dust); deterministic fixed-order sums; updates state (ping-pong).
__global__ __launch_bounds__(256) void sink_cfin_k(const float* __restrict__ colpart,
        const float* __restrict__ rsum_part, const float* __restrict__ stPrev,
        float* __restrict__ cperm, float* __restrict__ stNew, const float* __restrict__ scal) {
    __shared__ float wsum[4];
    int b = blockIdx.y;
    int t = threadIdx.x;
    int p = blockIdx.x * 256 + t;                      // float4 slot 0..1023
    float kd = scal[1];
    float c_dust_prev = stPrev[b];
    float sum_c_prev = ((stPrev[NB + b * NFIN + 0] + stPrev[NB + b * NFIN + 1])
                      + stPrev[NB + b * NFIN + 2]) + stPrev[NB + b * NFIN + 3];
    float r_dust = 0.5f / (kd * sum_c_prev + c_dust_prev);
    const float4* cp = (const float4*)colpart + (size_t)b * NBLK * 1024 + p;
    float4 a = make_float4(0.0f, 0.0f, 0.0f, 0.0f);
#pragma unroll 4
    for (int blk = 0; blk < NBLK; blk++) {
        float4 x = cp[(size_t)blk * 1024];
        a.x += x.x; a.y += x.y; a.z += x.z; a.w += x.w;
    }
    float db = kd * r_dust;
    float4 c4 = make_float4(MU / (a.x + db), MU / (a.y + db), MU / (a.z + db), MU / (a.w + db));
    ((float4*)cperm)[(size_t)b * 1024 + p] = c4;
    float ls = ((c4.x + c4.y) + c4.z) + c4.w;
#pragma unroll
    for (int off = 1; off < 64; off <<= 1) ls += __shfl_xor(ls, off);
    if ((t & 63) == 0) wsum[t >> 6] = ls;
    __syncthreads();
    if (t == 0) {
        stNew[NB + b * NFIN + blockIdx.x] = ((wsum[0] + wsum[1]) + wsum[2]) + wsum[3];
        if (blockIdx.x == 0) {
            float sum_r = 0.0f;
            for (int blk = 0; blk < NBLK; blk++) sum_r += rsum_part[b * NBLK + blk];
            stNew[b] = 0.5f / (kd * sum_r + r_dust);
        }
    }
}

// ---------------- v = log(c), un-permuting ----------------
__global__ void vlog_k(const float* __restrict__ cperm, float* __restrict__ v) {
    int i = blockIdx.x * 256 + threadIdx.x;   // 0..16383
    int b = i >> 12, x = i & 4095;
    int j = x & 3, p = x >> 2;
    int s = p >> 7, h = (p >> 6) & 1, l = p & 63;
    v[((size_t)b << 12) + 512 * s + 8 * l + 4 * h + j] = logf(cperm[i]);
}

// ---------------- posterior: mass/entropy/top-8 from fp32 sim ----------------
__global__ __launch_bounds__(256) void posterior_k(const float* __restrict__ sim, const float* __restrict__ r,
                                                   const float* __restrict__ v, const float* __restrict__ scal,
                                                   float* __restrict__ ent_out, int* __restrict__ tk_idx,
                                                   float* __restrict__ tk_logp) {
    __shared__ float vs[NN];
    int b = blockIdx.y;
    int t = threadIdx.x;
#pragma unroll
    for (int q = 0; q < 16; q++) vs[t + 256 * q] = v[(size_t)b * NN + t + 256 * q];
    __syncthreads();
    float ict = scal[0];
    int warp = t >> 6, lane = t & 63;
    int wv = blockIdx.x * 4 + warp;
    for (int j = 0; j < 4; j++) {
        int m = wv + 1024 * j;
        const float* Srow = sim + ((size_t)b * NN + m) * NN;
        float u = logf(r[(size_t)b * NN + m]);
        float mass = 0.0f, pl = 0.0f;
        float tv[8]; int ti[8];
#pragma unroll
        for (int k = 0; k < 8; k++) { tv[k] = -3.4e38f; ti[k] = 0x7fffffff; }
#pragma unroll 4
        for (int q = 0; q < 64; q++) {
            int n = lane + 64 * q;
            float s = Srow[n] * ict;
            s = fminf(fmaxf(s, -50.0f), 50.0f);
            float tt = s + vs[n];
            float l = tt + u;
            float lc = fminf(fmaxf(l, -50.0f), 0.0f);
            float p = __expf(lc);
            mass += p;
            pl = fmaf(p, lc, pl);
            if (tt > tv[7]) {                      // lane-local sorted top-8 (stable by index)
                tv[7] = tt; ti[7] = n;
#pragma unroll
                for (int k = 7; k > 0; k--) {
                    if (tv[k] > tv[k - 1]) {
                        float tmv = tv[k]; tv[k] = tv[k - 1]; tv[k - 1] = tmv;
                        int tmi = ti[k]; ti[k] = ti[k - 1]; ti[k - 1] = tmi;
                    }
                }
            }
        }
#pragma unroll
        for (int off = 32; off; off >>= 1) {
            mass += __shfl_down(mass, off);
            pl += __shfl_down(pl, off);
        }
        float outv[8]; int outi[8];
#pragma unroll
        for (int k = 0; k < 8; k++) {              // wave merge: max value, ties -> lower index
            float bv = tv[0]; int bi = ti[0];
#pragma unroll
            for (int off = 32; off; off >>= 1) {
                float ov = __shfl_down(bv, off); int oi = __shfl_down(bi, off);
                if (ov > bv || (ov == bv && oi < bi)) { bv = ov; bi = oi; }
            }
            bv = __shfl(bv, 0); bi = __shfl(bi, 0);
            outv[k] = bv; outi[k] = bi;
            if (ti[0] == bi) {                     // pop from the winning lane
#pragma unroll
                for (int k2 = 0; k2 < 7; k2++) { tv[k2] = tv[k2 + 1]; ti[k2] = ti[k2 + 1]; }
                tv[7] = -3.4e38f; ti[7] = 0x7fffffff;
            }
        }
        if (lane == 0) {
            float rm = fmaxf(mass, 1e-8f);
            float ent = (logf(rm) * mass - pl) / rm;
            float valid = fminf(fmaxf(rm * 8192.0f, 0.0f), 1.0f);
            ent_out[(size_t)b * NN + m] = ent * valid;
            size_t base = ((size_t)b * NN + m) * 8;
#pragma unroll
            for (int k = 0; k < 8; k++) { tk_idx[base + k] = outi[k]; tk_logp[base + k] = outv[k] + u; }
        }
    }
}

// ---------------- geometric consistency ----------------
__global__ __launch_bounds__(256) void geo_k(const int* __restrict__ tk_idx, const float* __restrict__ posA,
                                             const float* __restrict__ posB, float* __restrict__ geo_out) {
    __shared__ float dx[NN], dy[NN];
    int k = blockIdx.x, b = blockIdx.y;
    int t = threadIdx.x;
    const float2* pA = (const float2*)posA + (size_t)b * NN;
    const float2* pB = (const float2*)posB + (size_t)b * NN;
    for (int q = 0; q < 16; q++) {
        int n = t + 256 * q;
        int idx = tk_idx[((size_t)(b * NN + n)) * 8 + k];
        float2 pb = pB[idx];
        float2 pa = pA[n];
        dx[n] = pb.x - pa.x;
        dy[n] = pb.y - pa.y;
    }
    __syncthreads();
    for (int q = 0; q < 16; q++) {
        int n = t + 256 * q;
        int y = n >> 6, x = n & 63;
        int y0 = max(y - 3, 0), y1 = min(y + 3, 63);
        int x0 = max(x - 3, 0), x1 = min(x + 3, 63);
        float sx = 0, sxx = 0, sy = 0, syy = 0;
        for (int yy = y0; yy <= y1; yy++)
            for (int xx = x0; xx <= x1; xx++) {
                float a = dx[(yy << 6) + xx], c2 = dy[(yy << 6) + xx];
                sx += a; sxx = fmaf(a, a, sxx);
                sy += c2; syy = fmaf(c2, c2, syy);
            }
        float inv = 1.0f / (float)((y1 - y0 + 1) * (x1 - x0 + 1));
        float mx = sx * inv, my = sy * inv;
        float vx = fmaxf(sxx * inv - mx * mx, 0.0f);
        float vy = fmaxf(syy * inv - my * my, 0.0f);
        geo_out[((size_t)(b * NN + n)) * 8 + k] = 1.0f / (1.0f + (vx + vy) * 100.0f);
    }
}

// ---------------- refine: softmax-weighted positions ----------------
__global__ __launch_bounds__(256) void refine_k(const float* __restrict__ tk_logp, const int* __restrict__ tk_idx,
                                                const float* __restrict__ geo, const float* __restrict__ posB,
                                                const float* __restrict__ scal, float* __restrict__ refined) {
    int i = blockIdx.x * 256 + threadIdx.x;    // 0..16383
    int b = i >> 12;
    float gw = scal[2];
    const float* lp = tk_logp + (size_t)i * 8;
    const float* gs = geo + (size_t)i * 8;
    const int* ix = tk_idx + (size_t)i * 8;
    const float2* pB = (const float2*)posB + (size_t)b * NN;
    float cb[8]; float mx = -3.4e38f;
#pragma unroll
    for (int k = 0; k < 8; k++) { cb[k] = fmaf(gw, gs[k], lp[k]); mx = fmaxf(mx, cb[k]); }
    float sum = 0.0f, px = 0.0f, py = 0.0f;
#pragma unroll
    for (int k = 0; k < 8; k++) {
        float w = __expf(cb[k] - mx);
        float2 p = pB[ix[k]];
        sum += w; px = fmaf(w, p.x, px); py = fmaf(w, p.y, py);
    }
    float inv = 1.0f / sum;
    px = fminf(fmaxf(px * inv, -1.5f), 1.5f);
    py = fminf(fmaxf(py * inv, -1.5f), 1.5f);
    ((float2*)refined)[i] = make_float2(px, py);
}

extern "C" void kernel_launch(void* const* d_in, const int* in_sizes, int n_in,
                              void* d_out, int out_size, void* d_ws, size_t ws_size,
                              hipStream_t stream) {
    (void)in_sizes; (void)n_in; (void)out_size; (void)ws_size;
    const float* feat_A = (const float*)d_in[0];
    const float* feat_B = (const float*)d_in[1];
    const float* pos_A = (const float*)d_in[2];
    const float* pos_B = (const float*)d_in[3];
    const float* dsc = (const float*)d_in[4];
    const float* gwp = (const float*)d_in[5];
    const float* ctp = (const float*)d_in[6];

    float* out = (float*)d_out;
    float* out_refined = out;                       // [4,4096,2]
    float* out_entropy = out + 32768;               // [4,4096]
    float* out_sim = out + 49152;                   // [4,4096,4096]
    float* out_geo = out + 49152 + (size_t)NB * NN * NN;  // [4,4096,8]

    char* ws = (char*)d_ws;
    size_t off = 0;
    float* scal = (float*)(ws + off); off += 256;
    float* invA = (float*)(ws + off); off += (size_t)NB * NN * 4;
    float* invB = (float*)(ws + off); off += (size_t)NB * NN * 4;
    float* rr   = (float*)(ws + off); off += (size_t)NB * NN * 4;
    float* cperm = (float*)(ws + off); off += (size_t)NB * NN * 4;
    float* vv   = (float*)(ws + off); off += (size_t)NB * NN * 4;
    float* stA  = (float*)(ws + off); off += 256;
    float* stB  = (float*)(ws + off); off += 256;
    float* rsum_part = (float*)(ws + off); off += (size_t)NB * NBLK * 4;
    float* colpart = (float*)(ws + off); off += (size_t)NB * NBLK * NN * 4;   // 16.8 MB
    int* tki = (int*)(ws + off); off += (size_t)NB * NN * 8 * 4;
    float* tkl = (float*)(ws + off); off += (size_t)NB * NN * 8 * 4;

    scalars_k<<<1, 64, 0, stream>>>(dsc, gwp, ctp, scal);
    invnorm_k<<<8192, 256, 0, stream>>>(feat_A, feat_B, invA, invB);
    gemm_k<<<dim3(32, 32, NB), 256, 0, stream>>>(feat_A, feat_B, invA, invB, out_sim);
    init_sink2_k<<<64, 256, 0, stream>>>(cperm, stA);
    float* stIn = stA; float* stOut = stB;
    for (int it = 0; it < 15; it++) {
        sink_rc_k<<<dim3(NBLK, NB), 256, 0, stream>>>(out_sim, cperm, stIn, rr, rsum_part, colpart, scal);
        sink_cfin_k<<<dim3(NFIN, NB), 256, 0, stream>>>(colpart, rsum_part, stIn, cperm, stOut, scal);
        float* tmp = stIn; stIn = stOut; stOut = tmp;
    }
    vlog_k<<<64, 256, 0, stream>>>(cperm, vv);
    posterior_k<<<dim3(256, NB), 256, 0, stream>>>(out_sim, rr, vv, scal, out_entropy, tki, tkl);
    geo_k<<<dim3(8, NB), 256, 0, stream>>>(tki, pos_A, pos_B, out_geo);
    refine_k<<<64, 256, 0, stream>>>(tkl, tki, out_geo, pos_B, scal, out_refined);
}

// Round 3
// 1545.854 us; speedup vs baseline: 1.2068x; 1.2068x over previous
//
#include <hip/hip_runtime.h>
#include <hip/hip_fp16.h>
#include <math.h>

#define NB 4
#define NN 4096
#define NC 128
#define MU (1.0f/8192.0f)
#define NBLK 128   // row-panel blocks per batch (32 rows each) in fused sinkhorn pass
#define NFIN 32    // finalize blocks per batch (col-sum partial slots)

// ---------------- scalars ----------------
__global__ void scalars_k(const float* __restrict__ ds, const float* __restrict__ gw,
                          const float* __restrict__ ct, float* __restrict__ scal) {
    if (threadIdx.x == 0) {
        float t = ct[0];
        scal[0] = 1.0f / t;                                   // raw temp reciprocal (scores = sim/temp_raw)
        float tc = fminf(fmaxf(t, 0.03f), 10.0f);
        float d = fminf(fmaxf(ds[0] / tc, -50.0f), 50.0f);
        scal[1] = __expf(d);                                  // kd = exp(dustbin/temp_clipped)
        scal[2] = fminf(fmaxf(gw[0], 0.0f), 2.0f);            // clipped geo weight
    }
}

// ---------------- inverse norms ----------------
__global__ __launch_bounds__(256) void invnorm_k(const float* __restrict__ fA, const float* __restrict__ fB,
                                                 float* __restrict__ invA, float* __restrict__ invB) {
    int wv = blockIdx.x * 4 + (threadIdx.x >> 6);   // 0..32767
    int lane = threadIdx.x & 63;
    const float* src;
    float* dst;
    if (wv < NB * NN) { src = fA + (size_t)wv * NC; dst = invA + wv; }
    else              { src = fB + (size_t)(wv - NB * NN) * NC; dst = invB + (wv - NB * NN); }
    float2 x = *(const float2*)(src + 2 * lane);
    float ss = x.x * x.x + x.y * x.y;
#pragma unroll
    for (int off = 32; off; off >>= 1) ss += __shfl_down(ss, off);
    if (lane == 0) *dst = 1.0f / fmaxf(sqrtf(ss), 1e-12f);
}

// ---------------- fp32 GEMM: raw_sim ----------------
__global__ __launch_bounds__(256) void gemm_k(const float* __restrict__ A, const float* __restrict__ B,
                                              const float* __restrict__ invA, const float* __restrict__ invB,
                                              float* __restrict__ sim_out) {
    __shared__ float As[16][128];
    __shared__ float Bs[16][128];
    int b = blockIdx.z;
    int m0 = blockIdx.y * 128, n0 = blockIdx.x * 128;
    const float* Ab = A + (size_t)b * NN * NC;
    const float* Bb = B + (size_t)b * NN * NC;
    int t = threadIdx.x;
    int tr = t >> 2, tq = t & 3;
    int ty = t >> 4, tx = t & 15;
    float acc[8][8] = {};
    for (int k0 = 0; k0 < NC; k0 += 16) {
        float4 a0 = *(const float4*)(Ab + (size_t)(m0 + tr) * NC + k0 + 4 * tq);
        float4 a1 = *(const float4*)(Ab + (size_t)(m0 + tr + 64) * NC + k0 + 4 * tq);
        float4 b0 = *(const float4*)(Bb + (size_t)(n0 + tr) * NC + k0 + 4 * tq);
        float4 b1 = *(const float4*)(Bb + (size_t)(n0 + tr + 64) * NC + k0 + 4 * tq);
        __syncthreads();
        As[4 * tq + 0][tr] = a0.x; As[4 * tq + 1][tr] = a0.y; As[4 * tq + 2][tr] = a0.z; As[4 * tq + 3][tr] = a0.w;
        As[4 * tq + 0][tr + 64] = a1.x; As[4 * tq + 1][tr + 64] = a1.y; As[4 * tq + 2][tr + 64] = a1.z; As[4 * tq + 3][tr + 64] = a1.w;
        Bs[4 * tq + 0][tr] = b0.x; Bs[4 * tq + 1][tr] = b0.y; Bs[4 * tq + 2][tr] = b0.z; Bs[4 * tq + 3][tr] = b0.w;
        Bs[4 * tq + 0][tr + 64] = b1.x; Bs[4 * tq + 1][tr + 64] = b1.y; Bs[4 * tq + 2][tr + 64] = b1.z; Bs[4 * tq + 3][tr + 64] = b1.w;
        __syncthreads();
#pragma unroll
        for (int k = 0; k < 16; k++) {
            float av[8], bv[8];
            *(float4*)av = *(const float4*)&As[k][ty * 8];
            *(float4*)(av + 4) = *(const float4*)&As[k][ty * 8 + 4];
            *(float4*)bv = *(const float4*)&Bs[k][tx * 8];
            *(float4*)(bv + 4) = *(const float4*)&Bs[k][tx * 8 + 4];
#pragma unroll
            for (int i = 0; i < 8; i++)
#pragma unroll
                for (int j = 0; j < 8; j++) acc[i][j] = fmaf(av[i], bv[j], acc[i][j]);
        }
    }
    int m_base = m0 + ty * 8;
    int n_base = n0 + tx * 8;
    float ib[8];
#pragma unroll
    for (int j = 0; j < 8; j++) ib[j] = invB[(size_t)b * NN + n_base + j];
#pragma unroll
    for (int i = 0; i < 8; i++) {
        int m = m_base + i;
        float ia = invA[(size_t)b * NN + m];
        float row[8];
#pragma unroll
        for (int j = 0; j < 8; j++) row[j] = acc[i][j] * ia * ib[j];
        size_t rbase = ((size_t)b * NN + m) * NN + n_base;
        float4* so = (float4*)(sim_out + rbase);
        so[0] = make_float4(row[0], row[1], row[2], row[3]);
        so[1] = make_float4(row[4], row[5], row[6], row[7]);
    }
}

__device__ __forceinline__ float kval(float s, float ict) {
    float z = fminf(fmaxf(s * ict, -50.0f), 50.0f);
    return __expf(z);
}

// ---------------- Sinkhorn init ----------------
// cperm = 1 everywhere; state slot A: c_dust=1, csum partials sum to 4096.
__global__ void init_sink2_k(float* __restrict__ cperm, float* __restrict__ st) {
    int i = blockIdx.x * 256 + threadIdx.x;   // 0..16383
    if (i < NB * NN) cperm[i] = 1.0f;
    if (i < NB) st[i] = 1.0f;
    if (i < NB * NFIN) st[NB + i] = (float)NN / (float)NFIN;
}

// ---------------- fused Sinkhorn row+col pass (fp32 sim input) ----------------
// One read of sim per iteration. Block owns 32 rows (8 per warp). Per row:
//   r_m = MU / (sum_n K_mn c_n + kd*c_dust);  then colacc[n] += K_mn * r_m (K row held in regs).
// Deterministic: butterfly reduce (fixed tree), serialized warp->LDS adds, fixed-order finalize.
// c is stored PERMUTED: float4 slot p = s*128 + h*64 + l holds cols n = 512s + 8l + 4h + {0..3}.
__global__ __launch_bounds__(256) void sink_rc_k(const float* __restrict__ sim,
        const float* __restrict__ cperm, const float* __restrict__ stPrev,
        float* __restrict__ r, float* __restrict__ rsum_part, float* __restrict__ colpart,
        const float* __restrict__ scal) {
    __shared__ float4 cls[1024];   // permuted c (16 KB)
    __shared__ float4 red[1024];   // cross-warp col-partial reduction (16 KB)
    __shared__ float wsum[4];
    int b = blockIdx.y, blk = blockIdx.x;
    int t = threadIdx.x, w = t >> 6, lane = t & 63;
    float kd = scal[1], ict = scal[0];
    float c_dust = stPrev[b];
    const float4* cp = (const float4*)cperm + (size_t)b * 1024;
#pragma unroll
    for (int q = 0; q < 4; q++) cls[t + 256 * q] = cp[t + 256 * q];
    __syncthreads();
    float colacc[64];
#pragma unroll
    for (int q = 0; q < 64; q++) colacc[q] = 0.0f;
    float rsum = 0.0f;
    const float* Sb = sim + (size_t)b * NN * NN;
#pragma unroll 1
    for (int i = 0; i < 8; i++) {
        int m = blk * 32 + w * 8 + i;
        const float4* Srow = (const float4*)(Sb + (size_t)m * NN);
        float kv[64];
        float acc0 = 0.0f, acc1 = 0.0f;
#pragma unroll
        for (int s = 0; s < 8; s++) {
            float4 v0 = Srow[128 * s + 2 * lane];
            float4 v1 = Srow[128 * s + 2 * lane + 1];
            float4 c0 = cls[128 * s + lane];
            float4 c1 = cls[128 * s + 64 + lane];
            float k0 = kval(v0.x, ict), k1 = kval(v0.y, ict), k2 = kval(v0.z, ict), k3 = kval(v0.w, ict);
            float k4 = kval(v1.x, ict), k5 = kval(v1.y, ict), k6 = kval(v1.z, ict), k7 = kval(v1.w, ict);
            kv[8 * s + 0] = k0; kv[8 * s + 1] = k1; kv[8 * s + 2] = k2; kv[8 * s + 3] = k3;
            kv[8 * s + 4] = k4; kv[8 * s + 5] = k5; kv[8 * s + 6] = k6; kv[8 * s + 7] = k7;
            acc0 = fmaf(k0, c0.x, acc0); acc0 = fmaf(k1, c0.y, acc0);
            acc0 = fmaf(k2, c0.z, acc0); acc0 = fmaf(k3, c0.w, acc0);
            acc1 = fmaf(k4, c1.x, acc1); acc1 = fmaf(k5, c1.y, acc1);
            acc1 = fmaf(k6, c1.z, acc1); acc1 = fmaf(k7, c1.w, acc1);
        }
        float acc = acc0 + acc1;
#pragma unroll
        for (int off = 1; off < 64; off <<= 1) acc += __shfl_xor(acc, off);   // fixed tree, all lanes identical
        float rm = MU / (acc + kd * c_dust);
        if (lane == 0) r[(size_t)b * NN + m] = rm;
        rsum += rm;
#pragma unroll
        for (int q = 0; q < 64; q++) colacc[q] = fmaf(kv[q], rm, colacc[q]);
    }
    if (lane == 0) wsum[w] = rsum;
    __syncthreads();
    if (w == 0) {
#pragma unroll
        for (int s = 0; s < 8; s++) {
            red[128 * s + lane]      = make_float4(colacc[8 * s + 0], colacc[8 * s + 1], colacc[8 * s + 2], colacc[8 * s + 3]);
            red[128 * s + 64 + lane] = make_float4(colacc[8 * s + 4], colacc[8 * s + 5], colacc[8 * s + 6], colacc[8 * s + 7]);
        }
    }
    __syncthreads();
    if (w == 1) {
#pragma unroll
        for (int s = 0; s < 8; s++) {
            float4 x = red[128 * s + lane];
            x.x += colacc[8 * s + 0]; x.y += colacc[8 * s + 1]; x.z += colacc[8 * s + 2]; x.w += colacc[8 * s + 3];
            red[128 * s + lane] = x;
            float4 y = red[128 * s + 64 + lane];
            y.x += colacc[8 * s + 4]; y.y += colacc[8 * s + 5]; y.z += colacc[8 * s + 6]; y.w += colacc[8 * s + 7];
            red[128 * s + 64 + lane] = y;
        }
    }
    __syncthreads();
    if (w == 2) {
#pragma unroll
        for (int s = 0; s < 8; s++) {
            float4 x = red[128 * s + lane];
            x.x += colacc[8 * s + 0]; x.y += colacc[8 * s + 1]; x.z += colacc[8 * s + 2]; x.w += colacc[8 * s + 3];
            red[128 * s + lane] = x;
            float4 y = red[128 * s + 64 + lane];
            y.x += colacc[8 * s + 4]; y.y += colacc[8 * s + 5]; y.z += colacc[8 * s + 6]; y.w += colacc[8 * s + 7];
            red[128 * s + 64 + lane] = y;
        }
    }
    __syncthreads();
    if (w == 3) {
#pragma unroll
        for (int s = 0; s < 8; s++) {
            float4 x = red[128 * s + lane];
            x.x += colacc[8 * s + 0]; x.y += colacc[8 * s + 1]; x.z += colacc[8 * s + 2]; x.w += colacc[8 * s + 3];
            red[128 * s + lane] = x;
            float4 y = red[128 * s + 64 + lane];
            y.x += colacc[8 * s + 4]; y.y += colacc[8 * s + 5]; y.z += colacc[8 * s + 6]; y.w += colacc[8 * s + 7];
            red[128 * s + 64 + lane] = y;
        }
    }
    __syncthreads();
    float4* op = (float4*)colpart + ((size_t)b * NBLK + blk) * 1024;
#pragma unroll
    for (int q = 0; q < 4; q++) op[t + 256 * q] = red[t + 256 * q];
    if (t == 0) rsum_part[b * NBLK + blk] = ((wsum[0] + wsum[1]) + wsum[2]) + wsum[3];
}

// ---------------- Sinkhorn col finalize (parallelized) ----------------
// c_n = MU / (sum_blk colpart + kd*r_dust); deterministic fixed-order sums; updates state (ping-pong).
__global__ __launch_bounds__(256) void sink_cfin_k(const float* __restrict__ colpart,
        const float* __restrict__ rsum_part, const float* __restrict__ stPrev,
        float* __restrict__ cperm, float* __restrict__ stNew, const float* __restrict__ scal) {
    __shared__ float4 red[8][32];
    int b = blockIdx.y;
    int t = threadIdx.x;
    int sl = blockIdx.x * 32 + (t & 31);               // float4 slot 0..1023
    int p = t >> 5;                                    // 8-way split over blk dimension
    float kd = scal[1];
    float c_dust_prev = stPrev[b];
    float sum_c_prev = 0.0f;
#pragma unroll
    for (int x = 0; x < NFIN; x++) sum_c_prev += stPrev[NB + b * NFIN + x];
    float r_dust = 0.5f / (kd * sum_c_prev + c_dust_prev);
    const float4* cp = (const float4*)colpart + (size_t)b * NBLK * 1024;
    float4 a = make_float4(0.0f, 0.0f, 0.0f, 0.0f);
#pragma unroll 4
    for (int k = 0; k < NBLK / 8; k++) {
        float4 x = cp[(size_t)(p * (NBLK / 8) + k) * 1024 + sl];
        a.x += x.x; a.y += x.y; a.z += x.z; a.w += x.w;
    }
    red[p][t & 31] = a;
    __syncthreads();
    if (p == 0) {
        float4 a0 = red[0][t];
#pragma unroll
        for (int q = 1; q < 8; q++) {
            float4 x = red[q][t];
            a0.x += x.x; a0.y += x.y; a0.z += x.z; a0.w += x.w;
        }
        float db = kd * r_dust;
        float4 c4 = make_float4(MU / (a0.x + db), MU / (a0.y + db), MU / (a0.z + db), MU / (a0.w + db));
        ((float4*)cperm)[(size_t)b * 1024 + sl] = c4;
        float ls = ((c4.x + c4.y) + c4.z) + c4.w;
#pragma unroll
        for (int off = 1; off < 32; off <<= 1) ls += __shfl_xor(ls, off);   // lanes 0..31 only
        if (t == 0) {
            stNew[NB + b * NFIN + blockIdx.x] = ls;
            if (blockIdx.x == 0) {
                float sum_r = 0.0f;
#pragma unroll
                for (int blk = 0; blk < NBLK; blk++) sum_r += rsum_part[b * NBLK + blk];
                stNew[b] = 0.5f / (kd * sum_r + r_dust);
            }
        }
    }
}

// ---------------- v = log(c), un-permuting into SWIZZLED layout ----------------
// vswz[(n&63)*64 + (n>>6)] = log c_n  (so posterior's per-element LDS read is conflict-free)
__global__ void vlog_k(const float* __restrict__ cperm, float* __restrict__ vswz) {
    int i = blockIdx.x * 256 + threadIdx.x;   // 0..16383
    int b = i >> 12, e = i & 4095;
    int j = e & 3, pslot = e >> 2;
    int s = pslot >> 7, h = (pslot >> 6) & 1, l = pslot & 63;
    int n = 512 * s + 8 * l + 4 * h + j;
    vswz[((size_t)b << 12) + ((n & 63) << 6) + (n >> 6)] = logf(cperm[i]);
}

// ---------------- posterior: mass/entropy/top-8 from fp32 sim ----------------
// Lane l scans contiguous cols [64l, 64l+64) of its row via float4 (increasing n => stable ties).
__global__ __launch_bounds__(256) void posterior_k(const float* __restrict__ sim, const float* __restrict__ r,
                                                   const float* __restrict__ vswz, const float* __restrict__ scal,
                                                   float* __restrict__ ent_out, int* __restrict__ tk_idx,
                                                   float* __restrict__ tk_logp) {
    __shared__ float vs[NN];   // swizzled: vs[(n&63)*64 + (n>>6)]
    int b = blockIdx.y;
    int t = threadIdx.x;
#pragma unroll
    for (int q = 0; q < 16; q++) vs[t + 256 * q] = vswz[(size_t)b * NN + t + 256 * q];
    __syncthreads();
    float ict = scal[0];
    int warp = t >> 6, lane = t & 63;
    int wv = blockIdx.x * 4 + warp;
    const float* Sb = sim + (size_t)b * NN * NN;
    for (int j4 = 0; j4 < 4; j4++) {
        int m = wv + 1024 * j4;
        const float4* Srow = (const float4*)(Sb + (size_t)m * NN);
        float u = logf(r[(size_t)b * NN + m]);
        float mass = 0.0f, pl = 0.0f;
        float tv[8]; int ti[8];
#pragma unroll
        for (int k = 0; k < 8; k++) { tv[k] = -3.4e38f; ti[k] = 0x7fffffff; }
#pragma unroll 4
        for (int s4 = 0; s4 < 16; s4++) {
            float4 q4 = Srow[16 * lane + s4];            // cols 64*lane + 4*s4 + {0..3}
            float zz[4] = {q4.x, q4.y, q4.z, q4.w};
#pragma unroll
            for (int jj = 0; jj < 4; jj++) {
                int n = 64 * lane + 4 * s4 + jj;
                float s = zz[jj] * ict;
                s = fminf(fmaxf(s, -50.0f), 50.0f);
                float tt = s + vs[((4 * s4 + jj) << 6) + lane];
                float l_ = tt + u;
                float lc = fminf(fmaxf(l_, -50.0f), 0.0f);
                float pp = __expf(lc);
                mass += pp;
                pl = fmaf(pp, lc, pl);
                if (tt > tv[7]) {                      // lane-local sorted top-8 (stable by index)
                    tv[7] = tt; ti[7] = n;
#pragma unroll
                    for (int k = 7; k > 0; k--) {
                        if (tv[k] > tv[k - 1]) {
                            float tmv = tv[k]; tv[k] = tv[k - 1]; tv[k - 1] = tmv;
                            int tmi = ti[k]; ti[k] = ti[k - 1]; ti[k - 1] = tmi;
                        }
                    }
                }
            }
        }
#pragma unroll
        for (int off = 32; off; off >>= 1) {
            mass += __shfl_down(mass, off);
            pl += __shfl_down(pl, off);
        }
        float outv[8]; int outi[8];
#pragma unroll
        for (int k = 0; k < 8; k++) {              // wave merge: max value, ties -> lower index
            float bv = tv[0]; int bi = ti[0];
#pragma unroll
            for (int off = 32; off; off >>= 1) {
                float ov = __shfl_down(bv, off); int oi = __shfl_down(bi, off);
                if (ov > bv || (ov == bv && oi < bi)) { bv = ov; bi = oi; }
            }
            bv = __shfl(bv, 0); bi = __shfl(bi, 0);
            outv[k] = bv; outi[k] = bi;
            if (ti[0] == bi) {                     // pop from the winning lane
#pragma unroll
                for (int k2 = 0; k2 < 7; k2++) { tv[k2] = tv[k2 + 1]; ti[k2] = ti[k2 + 1]; }
                tv[7] = -3.4e38f; ti[7] = 0x7fffffff;
            }
        }
        if (lane == 0) {
            float rm = fmaxf(mass, 1e-8f);
            float ent = (logf(rm) * mass - pl) / rm;
            float valid = fminf(fmaxf(rm * 8192.0f, 0.0f), 1.0f);
            ent_out[(size_t)b * NN + m] = ent * valid;
            size_t base = ((size_t)b * NN + m) * 8;
#pragma unroll
            for (int k = 0; k < 8; k++) { tk_idx[base + k] = outi[k]; tk_logp[base + k] = outv[k] + u; }
        }
    }
}

// ---------------- geometric consistency ----------------
__global__ __launch_bounds__(256) void geo_k(const int* __restrict__ tk_idx, const float* __restrict__ posA,
                                             const float* __restrict__ posB, float* __restrict__ geo_out) {
    __shared__ float dx[NN], dy[NN];
    int k = blockIdx.x, b = blockIdx.y;
    int t = threadIdx.x;
    const float2* pA = (const float2*)posA + (size_t)b * NN;
    const float2* pB = (const float2*)posB + (size_t)b * NN;
    for (int q = 0; q < 16; q++) {
        int n = t + 256 * q;
        int idx = tk_idx[((size_t)(b * NN + n)) * 8 + k];
        float2 pb = pB[idx];
        float2 pa = pA[n];
        dx[n] = pb.x - pa.x;
        dy[n] = pb.y - pa.y;
    }
    __syncthreads();
    for (int q = 0; q < 16; q++) {
        int n = t + 256 * q;
        int y = n >> 6, x = n & 63;
        int y0 = max(y - 3, 0), y1 = min(y + 3, 63);
        int x0 = max(x - 3, 0), x1 = min(x + 3, 63);
        float sx = 0, sxx = 0, sy = 0, syy = 0;
        for (int yy = y0; yy <= y1; yy++)
            for (int xx = x0; xx <= x1; xx++) {
                float a = dx[(yy << 6) + xx], c2 = dy[(yy << 6) + xx];
                sx += a; sxx = fmaf(a, a, sxx);
                sy += c2; syy = fmaf(c2, c2, syy);
            }
        float inv = 1.0f / (float)((y1 - y0 + 1) * (x1 - x0 + 1));
        float mx = sx * inv, my = sy * inv;
        float vx = fmaxf(sxx * inv - mx * mx, 0.0f);
        float vy = fmaxf(syy * inv - my * my, 0.0f);
        geo_out[((size_t)(b * NN + n)) * 8 + k] = 1.0f / (1.0f + (vx + vy) * 100.0f);
    }
}

// ---------------- refine: softmax-weighted positions ----------------
__global__ __launch_bounds__(256) void refine_k(const float* __restrict__ tk_logp, const int* __restrict__ tk_idx,
                                                const float* __restrict__ geo, const float* __restrict__ posB,
                                                const float* __restrict__ scal, float* __restrict__ refined) {
    int i = blockIdx.x * 256 + threadIdx.x;    // 0..16383
    int b = i >> 12;
    float gw = scal[2];
    const float* lp = tk_logp + (size_t)i * 8;
    const float* gs = geo + (size_t)i * 8;
    const int* ix = tk_idx + (size_t)i * 8;
    const float2* pB = (const float2*)posB + (size_t)b * NN;
    float cb[8]; float mx = -3.4e38f;
#pragma unroll
    for (int k = 0; k < 8; k++) { cb[k] = fmaf(gw, gs[k], lp[k]); mx = fmaxf(mx, cb[k]); }
    float sum = 0.0f, px = 0.0f, py = 0.0f;
#pragma unroll
    for (int k = 0; k < 8; k++) {
        float w = __expf(cb[k] - mx);
        float2 p = pB[ix[k]];
        sum += w; px = fmaf(w, p.x, px); py = fmaf(w, p.y, py);
    }
    float inv = 1.0f / sum;
    px = fminf(fmaxf(px * inv, -1.5f), 1.5f);
    py = fminf(fmaxf(py * inv, -1.5f), 1.5f);
    ((float2*)refined)[i] = make_float2(px, py);
}

extern "C" void kernel_launch(void* const* d_in, const int* in_sizes, int n_in,
                              void* d_out, int out_size, void* d_ws, size_t ws_size,
                              hipStream_t stream) {
    (void)in_sizes; (void)n_in; (void)out_size; (void)ws_size;
    const float* feat_A = (const float*)d_in[0];
    const float* feat_B = (const float*)d_in[1];
    const float* pos_A = (const float*)d_in[2];
    const float* pos_B = (const float*)d_in[3];
    const float* dsc = (const float*)d_in[4];
    const float* gwp = (const float*)d_in[5];
    const float* ctp = (const float*)d_in[6];

    float* out = (float*)d_out;
    float* out_refined = out;                       // [4,4096,2]
    float* out_entropy = out + 32768;               // [4,4096]
    float* out_sim = out + 49152;                   // [4,4096,4096]
    float* out_geo = out + 49152 + (size_t)NB * NN * NN;  // [4,4096,8]

    char* ws = (char*)d_ws;
    size_t off = 0;
    float* scal = (float*)(ws + off); off += 256;
    float* invA = (float*)(ws + off); off += (size_t)NB * NN * 4;
    float* invB = (float*)(ws + off); off += (size_t)NB * NN * 4;
    float* rr   = (float*)(ws + off); off += (size_t)NB * NN * 4;
    float* cperm = (float*)(ws + off); off += (size_t)NB * NN * 4;
    float* vv   = (float*)(ws + off); off += (size_t)NB * NN * 4;
    float* stA  = (float*)(ws + off); off += 1024;
    float* stB  = (float*)(ws + off); off += 1024;
    float* rsum_part = (float*)(ws + off); off += (size_t)NB * NBLK * 4;
    int* tki = (int*)(ws + off); off += (size_t)NB * NN * 8 * 4;
    float* tkl = (float*)(ws + off); off += (size_t)NB * NN * 8 * 4;
    float* colpart = (float*)(ws + off); off += (size_t)NB * NBLK * NN * 4;   // 8.4 MB

    scalars_k<<<1, 64, 0, stream>>>(dsc, gwp, ctp, scal);
    invnorm_k<<<8192, 256, 0, stream>>>(feat_A, feat_B, invA, invB);
    gemm_k<<<dim3(32, 32, NB), 256, 0, stream>>>(feat_A, feat_B, invA, invB, out_sim);
    init_sink2_k<<<64, 256, 0, stream>>>(cperm, stA);
    float* stIn = stA; float* stOut = stB;
    for (int it = 0; it < 15; it++) {
        sink_rc_k<<<dim3(NBLK, NB), 256, 0, stream>>>(out_sim, cperm, stIn, rr, rsum_part, colpart, scal);
        sink_cfin_k<<<dim3(NFIN, NB), 256, 0, stream>>>(colpart, rsum_part, stIn, cperm, stOut, scal);
        float* tmp = stIn; stIn = stOut; stOut = tmp;
    }
    vlog_k<<<64, 256, 0, stream>>>(cperm, vv);
    posterior_k<<<dim3(256, NB), 256, 0, stream>>>(out_sim, rr, vv, scal, out_entropy, tki, tkl);
    geo_k<<<dim3(8, NB), 256, 0, stream>>>(tki, pos_A, pos_B, out_geo);
    refine_k<<<64, 256, 0, stream>>>(tkl, tki, out_geo, pos_B, scal, out_refined);
}

// Round 4
// 1485.119 us; speedup vs baseline: 1.2562x; 1.0409x over previous
//
#include <hip/hip_runtime.h>
#include <hip/hip_fp16.h>
#include <math.h>

#define NB 4
#define NN 4096
#define NC 128
#define MU (1.0f/8192.0f)
#define NBLK 256   // row-panel blocks per batch (16 rows each) in fused sinkhorn pass
#define NFIN 32    // finalize blocks per batch (col-sum partial slots)

// ---------------- scalars ----------------
__global__ void scalars_k(const float* __restrict__ ds, const float* __restrict__ gw,
                          const float* __restrict__ ct, float* __restrict__ scal) {
    if (threadIdx.x == 0) {
        float t = ct[0];
        scal[0] = 1.0f / t;                                   // raw temp reciprocal (scores = sim/temp_raw)
        float tc = fminf(fmaxf(t, 0.03f), 10.0f);
        float d = fminf(fmaxf(ds[0] / tc, -50.0f), 50.0f);
        scal[1] = __expf(d);                                  // kd = exp(dustbin/temp_clipped)
        scal[2] = fminf(fmaxf(gw[0], 0.0f), 2.0f);            // clipped geo weight
    }
}

// ---------------- inverse norms ----------------
__global__ __launch_bounds__(256) void invnorm_k(const float* __restrict__ fA, const float* __restrict__ fB,
                                                 float* __restrict__ invA, float* __restrict__ invB) {
    int wv = blockIdx.x * 4 + (threadIdx.x >> 6);   // 0..32767
    int lane = threadIdx.x & 63;
    const float* src;
    float* dst;
    if (wv < NB * NN) { src = fA + (size_t)wv * NC; dst = invA + wv; }
    else              { src = fB + (size_t)(wv - NB * NN) * NC; dst = invB + (wv - NB * NN); }
    float2 x = *(const float2*)(src + 2 * lane);
    float ss = x.x * x.x + x.y * x.y;
#pragma unroll
    for (int off = 32; off; off >>= 1) ss += __shfl_down(ss, off);
    if (lane == 0) *dst = 1.0f / fmaxf(sqrtf(ss), 1e-12f);
}

// ---------------- fp32 GEMM: raw_sim ----------------
__global__ __launch_bounds__(256) void gemm_k(const float* __restrict__ A, const float* __restrict__ B,
                                              const float* __restrict__ invA, const float* __restrict__ invB,
                                              float* __restrict__ sim_out) {
    __shared__ float As[16][128];
    __shared__ float Bs[16][128];
    int b = blockIdx.z;
    int m0 = blockIdx.y * 128, n0 = blockIdx.x * 128;
    const float* Ab = A + (size_t)b * NN * NC;
    const float* Bb = B + (size_t)b * NN * NC;
    int t = threadIdx.x;
    int tr = t >> 2, tq = t & 3;
    int ty = t >> 4, tx = t & 15;
    float acc[8][8] = {};
    for (int k0 = 0; k0 < NC; k0 += 16) {
        float4 a0 = *(const float4*)(Ab + (size_t)(m0 + tr) * NC + k0 + 4 * tq);
        float4 a1 = *(const float4*)(Ab + (size_t)(m0 + tr + 64) * NC + k0 + 4 * tq);
        float4 b0 = *(const float4*)(Bb + (size_t)(n0 + tr) * NC + k0 + 4 * tq);
        float4 b1 = *(const float4*)(Bb + (size_t)(n0 + tr + 64) * NC + k0 + 4 * tq);
        __syncthreads();
        As[4 * tq + 0][tr] = a0.x; As[4 * tq + 1][tr] = a0.y; As[4 * tq + 2][tr] = a0.z; As[4 * tq + 3][tr] = a0.w;
        As[4 * tq + 0][tr + 64] = a1.x; As[4 * tq + 1][tr + 64] = a1.y; As[4 * tq + 2][tr + 64] = a1.z; As[4 * tq + 3][tr + 64] = a1.w;
        Bs[4 * tq + 0][tr] = b0.x; Bs[4 * tq + 1][tr] = b0.y; Bs[4 * tq + 2][tr] = b0.z; Bs[4 * tq + 3][tr] = b0.w;
        Bs[4 * tq + 0][tr + 64] = b1.x; Bs[4 * tq + 1][tr + 64] = b1.y; Bs[4 * tq + 2][tr + 64] = b1.z; Bs[4 * tq + 3][tr + 64] = b1.w;
        __syncthreads();
#pragma unroll
        for (int k = 0; k < 16; k++) {
            float av[8], bv[8];
            *(float4*)av = *(const float4*)&As[k][ty * 8];
            *(float4*)(av + 4) = *(const float4*)&As[k][ty * 8 + 4];
            *(float4*)bv = *(const float4*)&Bs[k][tx * 8];
            *(float4*)(bv + 4) = *(const float4*)&Bs[k][tx * 8 + 4];
#pragma unroll
            for (int i = 0; i < 8; i++)
#pragma unroll
                for (int j = 0; j < 8; j++) acc[i][j] = fmaf(av[i], bv[j], acc[i][j]);
        }
    }
    int m_base = m0 + ty * 8;
    int n_base = n0 + tx * 8;
    float ib[8];
#pragma unroll
    for (int j = 0; j < 8; j++) ib[j] = invB[(size_t)b * NN + n_base + j];
#pragma unroll
    for (int i = 0; i < 8; i++) {
        int m = m_base + i;
        float ia = invA[(size_t)b * NN + m];
        float row[8];
#pragma unroll
        for (int j = 0; j < 8; j++) row[j] = acc[i][j] * ia * ib[j];
        size_t rbase = ((size_t)b * NN + m) * NN + n_base;
        float4* so = (float4*)(sim_out + rbase);
        so[0] = make_float4(row[0], row[1], row[2], row[3]);
        so[1] = make_float4(row[4], row[5], row[6], row[7]);
    }
}

__device__ __forceinline__ float kval(float s, float ict) {
    float z = fminf(fmaxf(s * ict, -50.0f), 50.0f);
    return __expf(z);
}

// ---------------- Sinkhorn init ----------------
// cperm = 1 everywhere; state slot A: c_dust=1, csum partials sum to 4096.
__global__ void init_sink2_k(float* __restrict__ cperm, float* __restrict__ st) {
    int i = blockIdx.x * 256 + threadIdx.x;   // 0..16383
    if (i < NB * NN) cperm[i] = 1.0f;
    if (i < NB) st[i] = 1.0f;
    if (i < NB * NFIN) st[NB + i] = (float)NN / (float)NFIN;
}

// ---------------- fused Sinkhorn row+col pass (fp32 sim input) ----------------
// One read of sim per iteration. Block owns 16 rows (4 per warp). Per row:
//   r_m = MU / (sum_n K_mn c_n + kd*c_dust);  then colacc[n] += K_mn * r_m (K row held in regs).
// Deterministic: butterfly reduce (fixed tree), serialized warp->LDS adds, fixed-order finalize.
// c is stored PERMUTED: float4 slot p = s*128 + h*64 + l holds cols n = 512s + 8l + 4h + {0..3}.
__global__ __launch_bounds__(256) void sink_rc_k(const float* __restrict__ sim,
        const float* __restrict__ cperm, const float* __restrict__ stPrev,
        float* __restrict__ r, float* __restrict__ rsum_part, float* __restrict__ colpart,
        const float* __restrict__ scal) {
    __shared__ float4 cls[1024];   // permuted c (16 KB)
    __shared__ float4 red[1024];   // cross-warp col-partial reduction (16 KB)
    __shared__ float wsum[4];
    int b = blockIdx.y, blk = blockIdx.x;
    int t = threadIdx.x, w = t >> 6, lane = t & 63;
    float kd = scal[1], ict = scal[0];
    float c_dust = stPrev[b];
    const float4* cp = (const float4*)cperm + (size_t)b * 1024;
#pragma unroll
    for (int q = 0; q < 4; q++) cls[t + 256 * q] = cp[t + 256 * q];
    __syncthreads();
    float colacc[64];
#pragma unroll
    for (int q = 0; q < 64; q++) colacc[q] = 0.0f;
    float rsum = 0.0f;
    const float* Sb = sim + (size_t)b * NN * NN;
#pragma unroll 1
    for (int i = 0; i < 4; i++) {
        int m = blk * 16 + w * 4 + i;
        const float4* Srow = (const float4*)(Sb + (size_t)m * NN);
        float kv[64];
        float acc0 = 0.0f, acc1 = 0.0f;
#pragma unroll
        for (int s = 0; s < 8; s++) {
            float4 v0 = Srow[128 * s + 2 * lane];
            float4 v1 = Srow[128 * s + 2 * lane + 1];
            float4 c0 = cls[128 * s + lane];
            float4 c1 = cls[128 * s + 64 + lane];
            float k0 = kval(v0.x, ict), k1 = kval(v0.y, ict), k2 = kval(v0.z, ict), k3 = kval(v0.w, ict);
            float k4 = kval(v1.x, ict), k5 = kval(v1.y, ict), k6 = kval(v1.z, ict), k7 = kval(v1.w, ict);
            kv[8 * s + 0] = k0; kv[8 * s + 1] = k1; kv[8 * s + 2] = k2; kv[8 * s + 3] = k3;
            kv[8 * s + 4] = k4; kv[8 * s + 5] = k5; kv[8 * s + 6] = k6; kv[8 * s + 7] = k7;
            acc0 = fmaf(k0, c0.x, acc0); acc0 = fmaf(k1, c0.y, acc0);
            acc0 = fmaf(k2, c0.z, acc0); acc0 = fmaf(k3, c0.w, acc0);
            acc1 = fmaf(k4, c1.x, acc1); acc1 = fmaf(k5, c1.y, acc1);
            acc1 = fmaf(k6, c1.z, acc1); acc1 = fmaf(k7, c1.w, acc1);
        }
        float acc = acc0 + acc1;
#pragma unroll
        for (int off = 1; off < 64; off <<= 1) acc += __shfl_xor(acc, off);   // fixed tree, all lanes identical
        float rm = MU / (acc + kd * c_dust);
        if (lane == 0) r[(size_t)b * NN + m] = rm;
        rsum += rm;
#pragma unroll
        for (int q = 0; q < 64; q++) colacc[q] = fmaf(kv[q], rm, colacc[q]);
    }
    if (lane == 0) wsum[w] = rsum;
    __syncthreads();
    if (w == 0) {
#pragma unroll
        for (int s = 0; s < 8; s++) {
            red[128 * s + lane]      = make_float4(colacc[8 * s + 0], colacc[8 * s + 1], colacc[8 * s + 2], colacc[8 * s + 3]);
            red[128 * s + 64 + lane] = make_float4(colacc[8 * s + 4], colacc[8 * s + 5], colacc[8 * s + 6], colacc[8 * s + 7]);
        }
    }
    __syncthreads();
    if (w == 1) {
#pragma unroll
        for (int s = 0; s < 8; s++) {
            float4 x = red[128 * s + lane];
            x.x += colacc[8 * s + 0]; x.y += colacc[8 * s + 1]; x.z += colacc[8 * s + 2]; x.w += colacc[8 * s + 3];
            red[128 * s + lane] = x;
            float4 y = red[128 * s + 64 + lane];
            y.x += colacc[8 * s + 4]; y.y += colacc[8 * s + 5]; y.z += colacc[8 * s + 6]; y.w += colacc[8 * s + 7];
            red[128 * s + 64 + lane] = y;
        }
    }
    __syncthreads();
    if (w == 2) {
#pragma unroll
        for (int s = 0; s < 8; s++) {
            float4 x = red[128 * s + lane];
            x.x += colacc[8 * s + 0]; x.y += colacc[8 * s + 1]; x.z += colacc[8 * s + 2]; x.w += colacc[8 * s + 3];
            red[128 * s + lane] = x;
            float4 y = red[128 * s + 64 + lane];
            y.x += colacc[8 * s + 4]; y.y += colacc[8 * s + 5]; y.z += colacc[8 * s + 6]; y.w += colacc[8 * s + 7];
            red[128 * s + 64 + lane] = y;
        }
    }
    __syncthreads();
    if (w == 3) {
#pragma unroll
        for (int s = 0; s < 8; s++) {
            float4 x = red[128 * s + lane];
            x.x += colacc[8 * s + 0]; x.y += colacc[8 * s + 1]; x.z += colacc[8 * s + 2]; x.w += colacc[8 * s + 3];
            red[128 * s + lane] = x;
            float4 y = red[128 * s + 64 + lane];
            y.x += colacc[8 * s + 4]; y.y += colacc[8 * s + 5]; y.z += colacc[8 * s + 6]; y.w += colacc[8 * s + 7];
            red[128 * s + 64 + lane] = y;
        }
    }
    __syncthreads();
    float4* op = (float4*)colpart + ((size_t)b * NBLK + blk) * 1024;
#pragma unroll
    for (int q = 0; q < 4; q++) op[t + 256 * q] = red[t + 256 * q];
    if (t == 0) rsum_part[b * NBLK + blk] = ((wsum[0] + wsum[1]) + wsum[2]) + wsum[3];
}

// ---------------- Sinkhorn col finalize (parallelized) ----------------
// c_n = MU / (sum_blk colpart + kd*r_dust); deterministic fixed-order sums; updates state (ping-pong).
__global__ __launch_bounds__(256) void sink_cfin_k(const float* __restrict__ colpart,
        const float* __restrict__ rsum_part, const float* __restrict__ stPrev,
        float* __restrict__ cperm, float* __restrict__ stNew, const float* __restrict__ scal) {
    __shared__ float4 red[8][32];
    int b = blockIdx.y;
    int t = threadIdx.x;
    int sl = blockIdx.x * 32 + (t & 31);               // float4 slot 0..1023
    int p = t >> 5;                                    // 8-way split over blk dimension
    float kd = scal[1];
    float c_dust_prev = stPrev[b];
    float sum_c_prev = 0.0f;
#pragma unroll
    for (int x = 0; x < NFIN; x++) sum_c_prev += stPrev[NB + b * NFIN + x];
    float r_dust = 0.5f / (kd * sum_c_prev + c_dust_prev);
    const float4* cp = (const float4*)colpart + (size_t)b * NBLK * 1024;
    float4 a = make_float4(0.0f, 0.0f, 0.0f, 0.0f);
#pragma unroll 4
    for (int k = 0; k < NBLK / 8; k++) {
        float4 x = cp[(size_t)(p * (NBLK / 8) + k) * 1024 + sl];
        a.x += x.x; a.y += x.y; a.z += x.z; a.w += x.w;
    }
    red[p][t & 31] = a;
    __syncthreads();
    if (p == 0) {
        float4 a0 = red[0][t];
#pragma unroll
        for (int q = 1; q < 8; q++) {
            float4 x = red[q][t];
            a0.x += x.x; a0.y += x.y; a0.z += x.z; a0.w += x.w;
        }
        float db = kd * r_dust;
        float4 c4 = make_float4(MU / (a0.x + db), MU / (a0.y + db), MU / (a0.z + db), MU / (a0.w + db));
        ((float4*)cperm)[(size_t)b * 1024 + sl] = c4;
        float ls = ((c4.x + c4.y) + c4.z) + c4.w;
#pragma unroll
        for (int off = 1; off < 32; off <<= 1) ls += __shfl_xor(ls, off);   // lanes 0..31 only
        if (t == 0) stNew[NB + b * NFIN + blockIdx.x] = ls;
    }
    // warp 1 (threads 64..127): deterministic lane-parallel sum of rsum_part -> new c_dust
    if (blockIdx.x == 0 && t >= 64 && t < 128) {
        int lane = t - 64;
        float s4 = 0.0f;
#pragma unroll
        for (int q = 0; q < NBLK / 64; q++) s4 += rsum_part[b * NBLK + lane + 64 * q];
#pragma unroll
        for (int off = 1; off < 64; off <<= 1) s4 += __shfl_xor(s4, off);   // fixed tree
        if (lane == 0) stNew[b] = 0.5f / (kd * s4 + r_dust);
    }
}

// ---------------- v = log(c), un-permuting to plain layout ----------------
__global__ void vlog_k(const float* __restrict__ cperm, float* __restrict__ v) {
    int i = blockIdx.x * 256 + threadIdx.x;   // 0..16383
    int b = i >> 12, e = i & 4095;
    int j = e & 3, pslot = e >> 2;
    int s = pslot >> 7, h = (pslot >> 6) & 1, l = pslot & 63;
    int n = 512 * s + 8 * l + 4 * h + j;
    v[((size_t)b << 12) + n] = logf(cperm[i]);
}

// ---------------- posterior: mass/entropy/top-8 from fp32 sim ----------------
// Wave-contiguous float4: per s4, lane l reads cols 4l + 256*s4 .. +3 (1KB/instr contiguous).
__global__ __launch_bounds__(256) void posterior_k(const float* __restrict__ sim, const float* __restrict__ r,
                                                   const float* __restrict__ v, const float* __restrict__ scal,
                                                   float* __restrict__ ent_out, int* __restrict__ tk_idx,
                                                   float* __restrict__ tk_logp) {
    __shared__ __align__(16) float vs[NN];
    int b = blockIdx.y;
    int t = threadIdx.x;
#pragma unroll
    for (int q = 0; q < 16; q++) vs[t + 256 * q] = v[(size_t)b * NN + t + 256 * q];
    __syncthreads();
    float ict = scal[0];
    int warp = t >> 6, lane = t & 63;
    int wv = blockIdx.x * 4 + warp;
    const float* Sb = sim + (size_t)b * NN * NN;
    const float4* vs4 = (const float4*)vs;
    for (int j4 = 0; j4 < 4; j4++) {
        int m = wv + 1024 * j4;
        const float4* Srow = (const float4*)(Sb + (size_t)m * NN);
        float u = logf(r[(size_t)b * NN + m]);
        float mass = 0.0f, pl = 0.0f;
        float tv[8]; int ti[8];
#pragma unroll
        for (int k = 0; k < 8; k++) { tv[k] = -3.4e38f; ti[k] = 0x7fffffff; }
#pragma unroll 4
        for (int s4 = 0; s4 < 16; s4++) {
            float4 q4 = Srow[lane + 64 * s4];            // cols 4*lane + 256*s4 + {0..3}
            float4 v4 = vs4[lane + 64 * s4];
            float zz[4] = {q4.x, q4.y, q4.z, q4.w};
            float vvv[4] = {v4.x, v4.y, v4.z, v4.w};
#pragma unroll
            for (int jj = 0; jj < 4; jj++) {
                int n = 4 * lane + 256 * s4 + jj;
                float s = zz[jj] * ict;
                s = fminf(fmaxf(s, -50.0f), 50.0f);
                float tt = s + vvv[jj];
                float l_ = tt + u;
                float lc = fminf(fmaxf(l_, -50.0f), 0.0f);
                float pp = __expf(lc);
                mass += pp;
                pl = fmaf(pp, lc, pl);
                if (tt > tv[7]) {                      // lane-local sorted top-8 (stable by index)
                    tv[7] = tt; ti[7] = n;
#pragma unroll
                    for (int k = 7; k > 0; k--) {
                        if (tv[k] > tv[k - 1]) {
                            float tmv = tv[k]; tv[k] = tv[k - 1]; tv[k - 1] = tmv;
                            int tmi = ti[k]; ti[k] = ti[k - 1]; ti[k - 1] = tmi;
                        }
                    }
                }
            }
        }
#pragma unroll
        for (int off = 32; off; off >>= 1) {
            mass += __shfl_down(mass, off);
            pl += __shfl_down(pl, off);
        }
        float outv[8]; int outi[8];
#pragma unroll
        for (int k = 0; k < 8; k++) {              // wave merge: max value, ties -> lower index
            float bv = tv[0]; int bi = ti[0];
#pragma unroll
            for (int off = 32; off; off >>= 1) {
                float ov = __shfl_down(bv, off); int oi = __shfl_down(bi, off);
                if (ov > bv || (ov == bv && oi < bi)) { bv = ov; bi = oi; }
            }
            bv = __shfl(bv, 0); bi = __shfl(bi, 0);
            outv[k] = bv; outi[k] = bi;
            if (ti[0] == bi) {                     // pop from the winning lane
#pragma unroll
                for (int k2 = 0; k2 < 7; k2++) { tv[k2] = tv[k2 + 1]; ti[k2] = ti[k2 + 1]; }
                tv[7] = -3.4e38f; ti[7] = 0x7fffffff;
            }
        }
        if (lane == 0) {
            float rm = fmaxf(mass, 1e-8f);
            float ent = (logf(rm) * mass - pl) / rm;
            float valid = fminf(fmaxf(rm * 8192.0f, 0.0f), 1.0f);
            ent_out[(size_t)b * NN + m] = ent * valid;
            size_t base = ((size_t)b * NN + m) * 8;
#pragma unroll
            for (int k = 0; k < 8; k++) { tk_idx[base + k] = outi[k]; tk_logp[base + k] = outv[k] + u; }
        }
    }
}

// ---------------- geometric consistency ----------------
__global__ __launch_bounds__(256) void geo_k(const int* __restrict__ tk_idx, const float* __restrict__ posA,
                                             const float* __restrict__ posB, float* __restrict__ geo_out) {
    __shared__ float dx[NN], dy[NN];
    int k = blockIdx.x, b = blockIdx.y;
    int t = threadIdx.x;
    const float2* pA = (const float2*)posA + (size_t)b * NN;
    const float2* pB = (const float2*)posB + (size_t)b * NN;
    for (int q = 0; q < 16; q++) {
        int n = t + 256 * q;
        int idx = tk_idx[((size_t)(b * NN + n)) * 8 + k];
        float2 pb = pB[idx];
        float2 pa = pA[n];
        dx[n] = pb.x - pa.x;
        dy[n] = pb.y - pa.y;
    }
    __syncthreads();
    for (int q = 0; q < 16; q++) {
        int n = t + 256 * q;
        int y = n >> 6, x = n & 63;
        int y0 = max(y - 3, 0), y1 = min(y + 3, 63);
        int x0 = max(x - 3, 0), x1 = min(x + 3, 63);
        float sx = 0, sxx = 0, sy = 0, syy = 0;
        for (int yy = y0; yy <= y1; yy++)
            for (int xx = x0; xx <= x1; xx++) {
                float a = dx[(yy << 6) + xx], c2 = dy[(yy << 6) + xx];
                sx += a; sxx = fmaf(a, a, sxx);
                sy += c2; syy = fmaf(c2, c2, syy);
            }
        float inv = 1.0f / (float)((y1 - y0 + 1) * (x1 - x0 + 1));
        float mx = sx * inv, my = sy * inv;
        float vx = fmaxf(sxx * inv - mx * mx, 0.0f);
        float vy = fmaxf(syy * inv - my * my, 0.0f);
        geo_out[((size_t)(b * NN + n)) * 8 + k] = 1.0f / (1.0f + (vx + vy) * 100.0f);
    }
}

// ---------------- refine: softmax-weighted positions ----------------
__global__ __launch_bounds__(256) void refine_k(const float* __restrict__ tk_logp, const int* __restrict__ tk_idx,
                                                const float* __restrict__ geo, const float* __restrict__ posB,
                                                const float* __restrict__ scal, float* __restrict__ refined) {
    int i = blockIdx.x * 256 + threadIdx.x;    // 0..16383
    int b = i >> 12;
    float gw = scal[2];
    const float* lp = tk_logp + (size_t)i * 8;
    const float* gs = geo + (size_t)i * 8;
    const int* ix = tk_idx + (size_t)i * 8;
    const float2* pB = (const float2*)posB + (size_t)b * NN;
    float cb[8]; float mx = -3.4e38f;
#pragma unroll
    for (int k = 0; k < 8; k++) { cb[k] = fmaf(gw, gs[k], lp[k]); mx = fmaxf(mx, cb[k]); }
    float sum = 0.0f, px = 0.0f, py = 0.0f;
#pragma unroll
    for (int k = 0; k < 8; k++) {
        float w = __expf(cb[k] - mx);
        float2 p = pB[ix[k]];
        sum += w; px = fmaf(w, p.x, px); py = fmaf(w, p.y, py);
    }
    float inv = 1.0f / sum;
    px = fminf(fmaxf(px * inv, -1.5f), 1.5f);
    py = fminf(fmaxf(py * inv, -1.5f), 1.5f);
    ((float2*)refined)[i] = make_float2(px, py);
}

extern "C" void kernel_launch(void* const* d_in, const int* in_sizes, int n_in,
                              void* d_out, int out_size, void* d_ws, size_t ws_size,
                              hipStream_t stream) {
    (void)in_sizes; (void)n_in; (void)out_size; (void)ws_size;
    const float* feat_A = (const float*)d_in[0];
    const float* feat_B = (const float*)d_in[1];
    const float* pos_A = (const float*)d_in[2];
    const float* pos_B = (const float*)d_in[3];
    const float* dsc = (const float*)d_in[4];
    const float* gwp = (const float*)d_in[5];
    const float* ctp = (const float*)d_in[6];

    float* out = (float*)d_out;
    float* out_refined = out;                       // [4,4096,2]
    float* out_entropy = out + 32768;               // [4,4096]
    float* out_sim = out + 49152;                   // [4,4096,4096]
    float* out_geo = out + 49152 + (size_t)NB * NN * NN;  // [4,4096,8]

    char* ws = (char*)d_ws;
    size_t off = 0;
    float* scal = (float*)(ws + off); off += 256;
    float* invA = (float*)(ws + off); off += (size_t)NB * NN * 4;
    float* invB = (float*)(ws + off); off += (size_t)NB * NN * 4;
    float* rr   = (float*)(ws + off); off += (size_t)NB * NN * 4;
    float* cperm = (float*)(ws + off); off += (size_t)NB * NN * 4;
    float* vv   = (float*)(ws + off); off += (size_t)NB * NN * 4;
    float* stA  = (float*)(ws + off); off += 1024;
    float* stB  = (float*)(ws + off); off += 1024;
    float* rsum_part = (float*)(ws + off); off += (size_t)NB * NBLK * 4;
    int* tki = (int*)(ws + off); off += (size_t)NB * NN * 8 * 4;
    float* tkl = (float*)(ws + off); off += (size_t)NB * NN * 8 * 4;
    float* colpart = (float*)(ws + off); off += (size_t)NB * NBLK * NN * 4;   // 16.8 MB

    scalars_k<<<1, 64, 0, stream>>>(dsc, gwp, ctp, scal);
    invnorm_k<<<8192, 256, 0, stream>>>(feat_A, feat_B, invA, invB);
    gemm_k<<<dim3(32, 32, NB), 256, 0, stream>>>(feat_A, feat_B, invA, invB, out_sim);
    init_sink2_k<<<64, 256, 0, stream>>>(cperm, stA);
    float* stIn = stA; float* stOut = stB;
    for (int it = 0; it < 15; it++) {
        sink_rc_k<<<dim3(NBLK, NB), 256, 0, stream>>>(out_sim, cperm, stIn, rr, rsum_part, colpart, scal);
        sink_cfin_k<<<dim3(NFIN, NB), 256, 0, stream>>>(colpart, rsum_part, stIn, cperm, stOut, scal);
        float* tmp = stIn; stIn = stOut; stOut = tmp;
    }
    vlog_k<<<64, 256, 0, stream>>>(cperm, vv);
    posterior_k<<<dim3(256, NB), 256, 0, stream>>>(out_sim, rr, vv, scal, out_entropy, tki, tkl);
    geo_k<<<dim3(8, NB), 256, 0, stream>>>(tki, pos_A, pos_B, out_geo);
    refine_k<<<64, 256, 0, stream>>>(tkl, tki, out_geo, pos_B, scal, out_refined);
}